// Round 1
// baseline (136.924 us; speedup 1.0000x reference)
//
#include <hip/hip_runtime.h>

#define BLOCK 256
#define NBLOCKS 2048
#define WAVES_PER_BLOCK (BLOCK / 64)

// Stage 1: wave-per-triplet gather + dot + online accumulate; per-block double partials.
__global__ __launch_bounds__(BLOCK) void triplet_partial_kernel(
    const float* __restrict__ emb,      // [N, 256] f32, rows unit-norm
    const int* __restrict__ trip,       // [T, 3] int32
    double* __restrict__ partial,       // [gridDim.x, 3]
    int T)
{
    const int lane = threadIdx.x & 63;
    const int wid  = threadIdx.x >> 6;
    const int nwaves = gridDim.x * WAVES_PER_BLOCK;
    const int gwave  = blockIdx.x * WAVES_PER_BLOCK + wid;

    const float4* __restrict__ emb4 = (const float4*)emb;  // 64 float4 per row

    float s_loss = 0.f;   // sum exp((an-ap)/margin)
    float s_apd  = 0.f;   // sum clipped ap dot
    float s_and  = 0.f;   // sum clipped an dot

    for (int t = gwave; t < T; t += nwaves) {
        const int ia = trip[3 * t + 0];
        const int ip = trip[3 * t + 1];
        const int ineg = trip[3 * t + 2];

        const float4 a = emb4[(size_t)ia * 64 + lane];
        const float4 p = emb4[(size_t)ip * 64 + lane];
        const float4 n = emb4[(size_t)ineg * 64 + lane];

        float dap = a.x * p.x + a.y * p.y + a.z * p.z + a.w * p.w;
        float dan = a.x * n.x + a.y * n.y + a.z * n.z + a.w * n.w;

        // 64-lane butterfly reduce (both dots)
        #pragma unroll
        for (int off = 1; off < 64; off <<= 1) {
            dap += __shfl_xor(dap, off, 64);
            dan += __shfl_xor(dan, off, 64);
        }

        dap = fminf(1.f, fmaxf(-1.f, dap));
        dan = fminf(1.f, fmaxf(-1.f, dan));

        if (lane == 0) {
            s_loss += expf((dan - dap) * (1.0f / 0.7f));
            s_apd  += dap;
            s_and  += dan;
        }
    }

    __shared__ double red[3][WAVES_PER_BLOCK];
    if (lane == 0) {
        red[0][wid] = (double)s_loss;
        red[1][wid] = (double)s_apd;
        red[2][wid] = (double)s_and;
    }
    __syncthreads();
    if (threadIdx.x == 0) {
        double l = 0.0, ap = 0.0, an = 0.0;
        #pragma unroll
        for (int w = 0; w < WAVES_PER_BLOCK; ++w) {
            l  += red[0][w];
            ap += red[1][w];
            an += red[2][w];
        }
        partial[(size_t)blockIdx.x * 3 + 0] = l;
        partial[(size_t)blockIdx.x * 3 + 1] = ap;
        partial[(size_t)blockIdx.x * 3 + 2] = an;
    }
}

// Stage 2: deterministic reduce of per-block partials, write 3 f32 outputs.
__global__ __launch_bounds__(256) void triplet_final_kernel(
    const double* __restrict__ partial, float* __restrict__ out, int nblocks, int T)
{
    __shared__ double red[256][3];
    double l = 0.0, ap = 0.0, an = 0.0;
    for (int i = threadIdx.x; i < nblocks; i += 256) {
        l  += partial[3 * (size_t)i + 0];
        ap += partial[3 * (size_t)i + 1];
        an += partial[3 * (size_t)i + 2];
    }
    red[threadIdx.x][0] = l;
    red[threadIdx.x][1] = ap;
    red[threadIdx.x][2] = an;
    __syncthreads();
    for (int s = 128; s > 0; s >>= 1) {
        if (threadIdx.x < s) {
            red[threadIdx.x][0] += red[threadIdx.x + s][0];
            red[threadIdx.x][1] += red[threadIdx.x + s][1];
            red[threadIdx.x][2] += red[threadIdx.x + s][2];
        }
        __syncthreads();
    }
    if (threadIdx.x == 0) {
        const double invT = 1.0 / (double)T;
        out[0] = (float)(red[0][0] * invT);          // mean exp loss
        out[1] = (float)(1.0 - red[0][1] * invT);    // mean(1 - ap_d)
        out[2] = (float)(1.0 - red[0][2] * invT);    // mean(1 - an_d)
    }
}

extern "C" void kernel_launch(void* const* d_in, const int* in_sizes, int n_in,
                              void* d_out, int out_size, void* d_ws, size_t ws_size,
                              hipStream_t stream) {
    const float* emb = (const float*)d_in[0];
    const int* trip  = (const int*)d_in[1];
    const int T = in_sizes[1] / 3;

    double* partial = (double*)d_ws;   // NBLOCKS * 3 doubles = 48 KiB

    triplet_partial_kernel<<<NBLOCKS, BLOCK, 0, stream>>>(emb, trip, partial, T);
    triplet_final_kernel<<<1, 256, 0, stream>>>(partial, (float*)d_out, NBLOCKS, T);
}

// Round 3
// 136.882 us; speedup vs baseline: 1.0003x; 1.0003x over previous
//
#include <hip/hip_runtime.h>

#define BLOCK 256
#define NBLOCKS 2048
#define WAVES_PER_BLOCK (BLOCK / 64)
#define GROUPS_PER_BLOCK (BLOCK / 16)

__device__ __forceinline__ float dot4(float4 a, float4 b) {
    return a.x * b.x + a.y * b.y + a.z * b.z + a.w * b.w;
}

// Stage 1: 16-lane group per triplet. 4 triplets per wave-iteration:
//   - 12 independent float4 gathers in flight per wave (4x MLP vs wave-per-triplet)
//   - 4-level shuffle reduce shared across 4 triplets (8 shuffle instrs vs 48)
//   - exp computed for 4 triplets per instruction
__global__ __launch_bounds__(BLOCK) void triplet_partial_kernel(
    const float* __restrict__ emb,      // [N, 256] f32
    const int* __restrict__ trip,       // [T, 3] int32
    double* __restrict__ partial,       // [gridDim.x, 3]
    int T)
{
    const int lane = threadIdx.x & 63;
    const int lg   = lane & 15;                       // lane within 16-group
    const int g0   = blockIdx.x * GROUPS_PER_BLOCK + (threadIdx.x >> 4);
    const int ngroups = gridDim.x * GROUPS_PER_BLOCK;

    const float4* __restrict__ emb4 = (const float4*)emb;  // 64 float4 per row

    float s_loss = 0.f, s_apd = 0.f, s_and = 0.f;

    for (int t = g0; t < T; t += ngroups) {
        const int ia = trip[3 * t + 0];
        const int ip = trip[3 * t + 1];
        const int in_ = trip[3 * t + 2];
        const size_t ba = (size_t)ia * 64 + lg;
        const size_t bp = (size_t)ip * 64 + lg;
        const size_t bn = (size_t)in_ * 64 + lg;

        // 12 independent 16B loads; each group slice is 256B contiguous.
        float4 a0 = emb4[ba], a1 = emb4[ba + 16], a2 = emb4[ba + 32], a3 = emb4[ba + 48];
        float4 p0 = emb4[bp], p1 = emb4[bp + 16], p2 = emb4[bp + 32], p3 = emb4[bp + 48];
        float4 n0 = emb4[bn], n1 = emb4[bn + 16], n2 = emb4[bn + 32], n3 = emb4[bn + 48];

        float dap = dot4(a0, p0) + dot4(a1, p1) + dot4(a2, p2) + dot4(a3, p3);
        float dan = dot4(a0, n0) + dot4(a1, n1) + dot4(a2, n2) + dot4(a3, n3);

        // reduce across the 16-lane group (xor offsets < 16 stay in-group)
        #pragma unroll
        for (int off = 1; off < 16; off <<= 1) {
            dap += __shfl_xor(dap, off, 64);
            dan += __shfl_xor(dan, off, 64);
        }

        dap = fminf(1.f, fmaxf(-1.f, dap));
        dan = fminf(1.f, fmaxf(-1.f, dan));

        // all 16 lanes of the group hold identical values; accumulate in all,
        // divide by 16 (exact) at the end.
        s_loss += expf((dan - dap) * (1.0f / 0.7f));
        s_apd  += dap;
        s_and  += dan;
    }

    // full-wave butterfly: each group's 16 identical copies sum exactly to
    // 16 * group_sum; multiply by 1/16 (power of two, exact).
    #pragma unroll
    for (int off = 1; off < 64; off <<= 1) {
        s_loss += __shfl_xor(s_loss, off, 64);
        s_apd  += __shfl_xor(s_apd,  off, 64);
        s_and  += __shfl_xor(s_and,  off, 64);
    }

    __shared__ double red[3][WAVES_PER_BLOCK];
    const int wid = threadIdx.x >> 6;
    if (lane == 0) {
        red[0][wid] = (double)s_loss * 0.0625;
        red[1][wid] = (double)s_apd  * 0.0625;
        red[2][wid] = (double)s_and  * 0.0625;
    }
    __syncthreads();
    if (threadIdx.x == 0) {
        double l = 0.0, ap = 0.0, an = 0.0;
        #pragma unroll
        for (int w = 0; w < WAVES_PER_BLOCK; ++w) {
            l  += red[0][w];
            ap += red[1][w];
            an += red[2][w];
        }
        partial[(size_t)blockIdx.x * 3 + 0] = l;
        partial[(size_t)blockIdx.x * 3 + 1] = ap;
        partial[(size_t)blockIdx.x * 3 + 2] = an;
    }
}

// Stage 2: deterministic reduce of per-block partials, write 3 f32 outputs.
__global__ __launch_bounds__(256) void triplet_final_kernel(
    const double* __restrict__ partial, float* __restrict__ out, int nblocks, int T)
{
    __shared__ double red[256][3];
    double l = 0.0, ap = 0.0, an = 0.0;
    for (int i = threadIdx.x; i < nblocks; i += 256) {
        l  += partial[3 * (size_t)i + 0];
        ap += partial[3 * (size_t)i + 1];
        an += partial[3 * (size_t)i + 2];
    }
    red[threadIdx.x][0] = l;
    red[threadIdx.x][1] = ap;
    red[threadIdx.x][2] = an;
    __syncthreads();
    for (int s = 128; s > 0; s >>= 1) {
        if (threadIdx.x < s) {
            red[threadIdx.x][0] += red[threadIdx.x + s][0];
            red[threadIdx.x][1] += red[threadIdx.x + s][1];
            red[threadIdx.x][2] += red[threadIdx.x + s][2];
        }
        __syncthreads();
    }
    if (threadIdx.x == 0) {
        const double invT = 1.0 / (double)T;
        out[0] = (float)(red[0][0] * invT);
        out[1] = (float)(1.0 - red[0][1] * invT);
        out[2] = (float)(1.0 - red[0][2] * invT);
    }
}

extern "C" void kernel_launch(void* const* d_in, const int* in_sizes, int n_in,
                              void* d_out, int out_size, void* d_ws, size_t ws_size,
                              hipStream_t stream) {
    const float* emb = (const float*)d_in[0];
    const int* trip  = (const int*)d_in[1];
    const int T = in_sizes[1] / 3;

    double* partial = (double*)d_ws;   // NBLOCKS * 3 doubles = 48 KiB

    triplet_partial_kernel<<<NBLOCKS, BLOCK, 0, stream>>>(emb, trip, partial, T);
    triplet_final_kernel<<<1, 256, 0, stream>>>(partial, (float*)d_out, NBLOCKS, T);
}

// Round 8
// 126.824 us; speedup vs baseline: 1.0796x; 1.0793x over previous
//
#include <hip/hip_runtime.h>
#include <hip/hip_fp16.h>

#define BLOCK 256
#define NBLOCKS 2048
#define WAVES_PER_BLOCK (BLOCK / 64)
#define GROUPS_PER_BLOCK (BLOCK / 16)
#define CONV_BLOCKS 2048

// ---------- fp16 path ----------

// Pass 0: convert f32 table -> fp16 table in d_ws (same element order).
__global__ __launch_bounds__(256) void convert_fp16_kernel(
    const float4* __restrict__ in4, uint4* __restrict__ out, int total8)
{
    const int stride = gridDim.x * blockDim.x;
    for (int i = blockIdx.x * blockDim.x + threadIdx.x; i < total8; i += stride) {
        float4 v0 = in4[2 * i];
        float4 v1 = in4[2 * i + 1];
        __half2 h0 = __floats2half2_rn(v0.x, v0.y);
        __half2 h1 = __floats2half2_rn(v0.z, v0.w);
        __half2 h2 = __floats2half2_rn(v1.x, v1.y);
        __half2 h3 = __floats2half2_rn(v1.z, v1.w);
        uint4 u;
        u.x = *(unsigned*)&h0; u.y = *(unsigned*)&h1;
        u.z = *(unsigned*)&h2; u.w = *(unsigned*)&h3;
        out[i] = u;
    }
}

__device__ __forceinline__ float dot_u4_h(uint4 a, uint4 b) {
    const __half2* ah = (const __half2*)&a;
    const __half2* bh = (const __half2*)&b;
    float s = 0.f;
    #pragma unroll
    for (int j = 0; j < 4; ++j) {
        float2 af = __half22float2(ah[j]);
        float2 bf = __half22float2(bh[j]);
        s += af.x * bf.x + af.y * bf.y;
    }
    return s;
}

// Stage 1 (fp16): 16-lane group per triplet; row = 32 uint4 (512B).
// Lane lg loads uint4 at row+lg and row+16+lg (both fully coalesced 256B slabs).
__global__ __launch_bounds__(BLOCK) void triplet_partial_fp16(
    const uint4* __restrict__ tab,      // [N*32] uint4 = fp16 table
    const int* __restrict__ trip,       // [T,3] int32
    double* __restrict__ partial,       // [gridDim.x,3]
    int T)
{
    const int lane = threadIdx.x & 63;
    const int lg   = lane & 15;
    const int g0   = blockIdx.x * GROUPS_PER_BLOCK + (threadIdx.x >> 4);
    const int ngroups = gridDim.x * GROUPS_PER_BLOCK;

    float s_loss = 0.f, s_apd = 0.f, s_and = 0.f;

    for (int t = g0; t < T; t += ngroups) {
        const int ia = trip[3 * t + 0];
        const int ip = trip[3 * t + 1];
        const int in_ = trip[3 * t + 2];
        const size_t ba = (size_t)ia * 32 + lg;
        const size_t bp = (size_t)ip * 32 + lg;
        const size_t bn = (size_t)in_ * 32 + lg;

        uint4 a0 = tab[ba], a1 = tab[ba + 16];
        uint4 p0 = tab[bp], p1 = tab[bp + 16];
        uint4 n0 = tab[bn], n1 = tab[bn + 16];

        float dap = dot_u4_h(a0, p0) + dot_u4_h(a1, p1);
        float dan = dot_u4_h(a0, n0) + dot_u4_h(a1, n1);

        #pragma unroll
        for (int off = 1; off < 16; off <<= 1) {
            dap += __shfl_xor(dap, off, 64);
            dan += __shfl_xor(dan, off, 64);
        }

        dap = fminf(1.f, fmaxf(-1.f, dap));
        dan = fminf(1.f, fmaxf(-1.f, dan));

        s_loss += expf((dan - dap) * (1.0f / 0.7f));
        s_apd  += dap;
        s_and  += dan;
    }

    #pragma unroll
    for (int off = 1; off < 64; off <<= 1) {
        s_loss += __shfl_xor(s_loss, off, 64);
        s_apd  += __shfl_xor(s_apd,  off, 64);
        s_and  += __shfl_xor(s_and,  off, 64);
    }

    __shared__ double red[3][WAVES_PER_BLOCK];
    const int wid = threadIdx.x >> 6;
    if (lane == 0) {
        red[0][wid] = (double)s_loss * 0.0625;
        red[1][wid] = (double)s_apd  * 0.0625;
        red[2][wid] = (double)s_and  * 0.0625;
    }
    __syncthreads();
    if (threadIdx.x == 0) {
        double l = 0.0, ap = 0.0, an = 0.0;
        #pragma unroll
        for (int w = 0; w < WAVES_PER_BLOCK; ++w) {
            l += red[0][w]; ap += red[1][w]; an += red[2][w];
        }
        partial[(size_t)blockIdx.x * 3 + 0] = l;
        partial[(size_t)blockIdx.x * 3 + 1] = ap;
        partial[(size_t)blockIdx.x * 3 + 2] = an;
    }
}

// ---------- f32 fallback path (R2 kernel, proven) ----------

__device__ __forceinline__ float dot4(float4 a, float4 b) {
    return a.x * b.x + a.y * b.y + a.z * b.z + a.w * b.w;
}

__global__ __launch_bounds__(BLOCK) void triplet_partial_kernel(
    const float* __restrict__ emb, const int* __restrict__ trip,
    double* __restrict__ partial, int T)
{
    const int lane = threadIdx.x & 63;
    const int lg   = lane & 15;
    const int g0   = blockIdx.x * GROUPS_PER_BLOCK + (threadIdx.x >> 4);
    const int ngroups = gridDim.x * GROUPS_PER_BLOCK;
    const float4* __restrict__ emb4 = (const float4*)emb;

    float s_loss = 0.f, s_apd = 0.f, s_and = 0.f;

    for (int t = g0; t < T; t += ngroups) {
        const int ia = trip[3 * t + 0];
        const int ip = trip[3 * t + 1];
        const int in_ = trip[3 * t + 2];
        const size_t ba = (size_t)ia * 64 + lg;
        const size_t bp = (size_t)ip * 64 + lg;
        const size_t bn = (size_t)in_ * 64 + lg;

        float4 a0 = emb4[ba], a1 = emb4[ba + 16], a2 = emb4[ba + 32], a3 = emb4[ba + 48];
        float4 p0 = emb4[bp], p1 = emb4[bp + 16], p2 = emb4[bp + 32], p3 = emb4[bp + 48];
        float4 n0 = emb4[bn], n1 = emb4[bn + 16], n2 = emb4[bn + 32], n3 = emb4[bn + 48];

        float dap = dot4(a0, p0) + dot4(a1, p1) + dot4(a2, p2) + dot4(a3, p3);
        float dan = dot4(a0, n0) + dot4(a1, n1) + dot4(a2, n2) + dot4(a3, n3);

        #pragma unroll
        for (int off = 1; off < 16; off <<= 1) {
            dap += __shfl_xor(dap, off, 64);
            dan += __shfl_xor(dan, off, 64);
        }

        dap = fminf(1.f, fmaxf(-1.f, dap));
        dan = fminf(1.f, fmaxf(-1.f, dan));

        s_loss += expf((dan - dap) * (1.0f / 0.7f));
        s_apd  += dap;
        s_and  += dan;
    }

    #pragma unroll
    for (int off = 1; off < 64; off <<= 1) {
        s_loss += __shfl_xor(s_loss, off, 64);
        s_apd  += __shfl_xor(s_apd,  off, 64);
        s_and  += __shfl_xor(s_and,  off, 64);
    }

    __shared__ double red[3][WAVES_PER_BLOCK];
    const int wid = threadIdx.x >> 6;
    if (lane == 0) {
        red[0][wid] = (double)s_loss * 0.0625;
        red[1][wid] = (double)s_apd  * 0.0625;
        red[2][wid] = (double)s_and  * 0.0625;
    }
    __syncthreads();
    if (threadIdx.x == 0) {
        double l = 0.0, ap = 0.0, an = 0.0;
        #pragma unroll
        for (int w = 0; w < WAVES_PER_BLOCK; ++w) {
            l += red[0][w]; ap += red[1][w]; an += red[2][w];
        }
        partial[(size_t)blockIdx.x * 3 + 0] = l;
        partial[(size_t)blockIdx.x * 3 + 1] = ap;
        partial[(size_t)blockIdx.x * 3 + 2] = an;
    }
}

// Stage 2: deterministic reduce of per-block partials.
__global__ __launch_bounds__(256) void triplet_final_kernel(
    const double* __restrict__ partial, float* __restrict__ out, int nblocks, int T)
{
    __shared__ double red[256][3];
    double l = 0.0, ap = 0.0, an = 0.0;
    for (int i = threadIdx.x; i < nblocks; i += 256) {
        l  += partial[3 * (size_t)i + 0];
        ap += partial[3 * (size_t)i + 1];
        an += partial[3 * (size_t)i + 2];
    }
    red[threadIdx.x][0] = l;
    red[threadIdx.x][1] = ap;
    red[threadIdx.x][2] = an;
    __syncthreads();
    for (int s = 128; s > 0; s >>= 1) {
        if (threadIdx.x < s) {
            red[threadIdx.x][0] += red[threadIdx.x + s][0];
            red[threadIdx.x][1] += red[threadIdx.x + s][1];
            red[threadIdx.x][2] += red[threadIdx.x + s][2];
        }
        __syncthreads();
    }
    if (threadIdx.x == 0) {
        const double invT = 1.0 / (double)T;
        out[0] = (float)(red[0][0] * invT);
        out[1] = (float)(1.0 - red[0][1] * invT);
        out[2] = (float)(1.0 - red[0][2] * invT);
    }
}

extern "C" void kernel_launch(void* const* d_in, const int* in_sizes, int n_in,
                              void* d_out, int out_size, void* d_ws, size_t ws_size,
                              hipStream_t stream) {
    const float* emb = (const float*)d_in[0];
    const int* trip  = (const int*)d_in[1];
    const int T = in_sizes[1] / 3;
    const size_t tabBytes = (size_t)in_sizes[0] * sizeof(__half);  // 32 MiB

    if (ws_size >= tabBytes + (size_t)NBLOCKS * 3 * sizeof(double)) {
        uint4* htab = (uint4*)d_ws;
        double* partial = (double*)((char*)d_ws + tabBytes);
        convert_fp16_kernel<<<CONV_BLOCKS, 256, 0, stream>>>(
            (const float4*)emb, htab, in_sizes[0] / 8);
        triplet_partial_fp16<<<NBLOCKS, BLOCK, 0, stream>>>(htab, trip, partial, T);
        triplet_final_kernel<<<1, 256, 0, stream>>>(partial, (float*)d_out, NBLOCKS, T);
    } else {
        double* partial = (double*)d_ws;
        triplet_partial_kernel<<<NBLOCKS, BLOCK, 0, stream>>>(emb, trip, partial, T);
        triplet_final_kernel<<<1, 256, 0, stream>>>(partial, (float*)d_out, NBLOCKS, T);
    }
}

// Round 11
// 112.704 us; speedup vs baseline: 1.2149x; 1.1253x over previous
//
#include <hip/hip_runtime.h>

#define BLOCK 256
#define NBLOCKS 2048
#define WAVES_PER_BLOCK (BLOCK / 64)
#define GROUPS_PER_BLOCK (BLOCK / 16)
#define CONV_BLOCKS 4096

// ---- int8 dot primitive: hardware sdot4 if available, else software ----
#if defined(__has_builtin)
#  if __has_builtin(__builtin_amdgcn_sdot4)
#    define SDOT4(a, b, c) __builtin_amdgcn_sdot4((a), (b), (c), false)
#  endif
#endif
#ifndef SDOT4
__device__ __forceinline__ int sdot4_sw(int a, int b, int c) {
    #pragma unroll
    for (int k = 0; k < 4; ++k) {
        int ae = (a << (24 - 8 * k)) >> 24;
        int be = (b << (24 - 8 * k)) >> 24;
        c += ae * be;
    }
    return c;
}
#  define SDOT4(a, b, c) sdot4_sw((a), (b), (c))
#endif

// Pass 0: f32 table -> int8 table (per-row symmetric scale) + f32 scales.
// One 64-lane wave per row: lane loads float4 (16B), wave-reduce max|x|,
// quantize to 4 int8 packed in one dword, coalesced 256B/row store.
__global__ __launch_bounds__(256) void convert_int8_kernel(
    const float4* __restrict__ emb4,    // [rows*64]
    unsigned int* __restrict__ q,       // [rows*64] 4 int8 per dword
    float* __restrict__ scl,            // [rows]
    int rows)
{
    const int lane = threadIdx.x & 63;
    const int wid  = blockIdx.x * (blockDim.x >> 6) + (threadIdx.x >> 6);
    const int nw   = gridDim.x * (blockDim.x >> 6);
    for (int r = wid; r < rows; r += nw) {
        float4 v = emb4[(size_t)r * 64 + lane];
        float m = fmaxf(fmaxf(fabsf(v.x), fabsf(v.y)), fmaxf(fabsf(v.z), fabsf(v.w)));
        #pragma unroll
        for (int off = 1; off < 64; off <<= 1)
            m = fmaxf(m, __shfl_xor(m, off, 64));
        const float inv = 127.0f / m;
        int q0 = __float2int_rn(v.x * inv) & 255;
        int q1 = __float2int_rn(v.y * inv) & 255;
        int q2 = __float2int_rn(v.z * inv) & 255;
        int q3 = __float2int_rn(v.w * inv) & 255;
        q[(size_t)r * 64 + lane] =
            (unsigned int)(q0 | (q1 << 8) | (q2 << 16) | (q3 << 24));
        if (lane == 0) scl[r] = m * (1.0f / 127.0f);
    }
}

// Stage 1 (int8): 16-lane group per triplet; row = 256B = 16 x uint4.
// Lane lg holds bytes [lg*16, lg*16+16) of each row -> 4 sdot4 per pair,
// exact integer 16-lane butterfly reduce, then scale/clip/exp in f32.
__global__ __launch_bounds__(BLOCK) void triplet_partial_int8(
    const uint4* __restrict__ tabq,     // [rows*16]
    const float* __restrict__ scl,      // [rows]
    const int* __restrict__ trip,       // [T,3] int32
    double* __restrict__ partial,       // [gridDim.x,3]
    int T)
{
    const int lane = threadIdx.x & 63;
    const int lg   = lane & 15;
    const int g0   = blockIdx.x * GROUPS_PER_BLOCK + (threadIdx.x >> 4);
    const int ngroups = gridDim.x * GROUPS_PER_BLOCK;

    float s_loss = 0.f, s_apd = 0.f, s_and = 0.f;

    for (int t = g0; t < T; t += ngroups) {
        const int ia = trip[3 * t + 0];
        const int ip = trip[3 * t + 1];
        const int in_ = trip[3 * t + 2];

        const float sa = scl[ia];
        const float sp = scl[ip];
        const float sn = scl[in_];

        uint4 qa = tabq[(size_t)ia * 16 + lg];
        uint4 qp = tabq[(size_t)ip * 16 + lg];
        uint4 qn = tabq[(size_t)in_ * 16 + lg];

        int idap = 0, idan = 0;
        idap = SDOT4((int)qa.x, (int)qp.x, idap);
        idap = SDOT4((int)qa.y, (int)qp.y, idap);
        idap = SDOT4((int)qa.z, (int)qp.z, idap);
        idap = SDOT4((int)qa.w, (int)qp.w, idap);
        idan = SDOT4((int)qa.x, (int)qn.x, idan);
        idan = SDOT4((int)qa.y, (int)qn.y, idan);
        idan = SDOT4((int)qa.z, (int)qn.z, idan);
        idan = SDOT4((int)qa.w, (int)qn.w, idan);

        // exact integer reduce across the 16-lane group
        #pragma unroll
        for (int off = 1; off < 16; off <<= 1) {
            idap += __shfl_xor(idap, off, 64);
            idan += __shfl_xor(idan, off, 64);
        }

        float dap = (float)idap * (sa * sp);
        float dan = (float)idan * (sa * sn);

        dap = fminf(1.f, fmaxf(-1.f, dap));
        dan = fminf(1.f, fmaxf(-1.f, dan));

        s_loss += expf((dan - dap) * (1.0f / 0.7f));
        s_apd  += dap;
        s_and  += dan;
    }

    // 16 identical copies per group; butterfly then x1/16 (exact pow2)
    #pragma unroll
    for (int off = 1; off < 64; off <<= 1) {
        s_loss += __shfl_xor(s_loss, off, 64);
        s_apd  += __shfl_xor(s_apd,  off, 64);
        s_and  += __shfl_xor(s_and,  off, 64);
    }

    __shared__ double red[3][WAVES_PER_BLOCK];
    const int wid = threadIdx.x >> 6;
    if (lane == 0) {
        red[0][wid] = (double)s_loss * 0.0625;
        red[1][wid] = (double)s_apd  * 0.0625;
        red[2][wid] = (double)s_and  * 0.0625;
    }
    __syncthreads();
    if (threadIdx.x == 0) {
        double l = 0.0, ap = 0.0, an = 0.0;
        #pragma unroll
        for (int w = 0; w < WAVES_PER_BLOCK; ++w) {
            l += red[0][w]; ap += red[1][w]; an += red[2][w];
        }
        partial[(size_t)blockIdx.x * 3 + 0] = l;
        partial[(size_t)blockIdx.x * 3 + 1] = ap;
        partial[(size_t)blockIdx.x * 3 + 2] = an;
    }
}

// ---------- f32 fallback path (proven) ----------

__device__ __forceinline__ float dot4(float4 a, float4 b) {
    return a.x * b.x + a.y * b.y + a.z * b.z + a.w * b.w;
}

__global__ __launch_bounds__(BLOCK) void triplet_partial_kernel(
    const float* __restrict__ emb, const int* __restrict__ trip,
    double* __restrict__ partial, int T)
{
    const int lane = threadIdx.x & 63;
    const int lg   = lane & 15;
    const int g0   = blockIdx.x * GROUPS_PER_BLOCK + (threadIdx.x >> 4);
    const int ngroups = gridDim.x * GROUPS_PER_BLOCK;
    const float4* __restrict__ emb4 = (const float4*)emb;

    float s_loss = 0.f, s_apd = 0.f, s_and = 0.f;

    for (int t = g0; t < T; t += ngroups) {
        const int ia = trip[3 * t + 0];
        const int ip = trip[3 * t + 1];
        const int in_ = trip[3 * t + 2];
        const size_t ba = (size_t)ia * 64 + lg;
        const size_t bp = (size_t)ip * 64 + lg;
        const size_t bn = (size_t)in_ * 64 + lg;

        float4 a0 = emb4[ba], a1 = emb4[ba + 16], a2 = emb4[ba + 32], a3 = emb4[ba + 48];
        float4 p0 = emb4[bp], p1 = emb4[bp + 16], p2 = emb4[bp + 32], p3 = emb4[bp + 48];
        float4 n0 = emb4[bn], n1 = emb4[bn + 16], n2 = emb4[bn + 32], n3 = emb4[bn + 48];

        float dap = dot4(a0, p0) + dot4(a1, p1) + dot4(a2, p2) + dot4(a3, p3);
        float dan = dot4(a0, n0) + dot4(a1, n1) + dot4(a2, n2) + dot4(a3, n3);

        #pragma unroll
        for (int off = 1; off < 16; off <<= 1) {
            dap += __shfl_xor(dap, off, 64);
            dan += __shfl_xor(dan, off, 64);
        }

        dap = fminf(1.f, fmaxf(-1.f, dap));
        dan = fminf(1.f, fmaxf(-1.f, dan));

        s_loss += expf((dan - dap) * (1.0f / 0.7f));
        s_apd  += dap;
        s_and  += dan;
    }

    #pragma unroll
    for (int off = 1; off < 64; off <<= 1) {
        s_loss += __shfl_xor(s_loss, off, 64);
        s_apd  += __shfl_xor(s_apd,  off, 64);
        s_and  += __shfl_xor(s_and,  off, 64);
    }

    __shared__ double red[3][WAVES_PER_BLOCK];
    const int wid = threadIdx.x >> 6;
    if (lane == 0) {
        red[0][wid] = (double)s_loss * 0.0625;
        red[1][wid] = (double)s_apd  * 0.0625;
        red[2][wid] = (double)s_and  * 0.0625;
    }
    __syncthreads();
    if (threadIdx.x == 0) {
        double l = 0.0, ap = 0.0, an = 0.0;
        #pragma unroll
        for (int w = 0; w < WAVES_PER_BLOCK; ++w) {
            l += red[0][w]; ap += red[1][w]; an += red[2][w];
        }
        partial[(size_t)blockIdx.x * 3 + 0] = l;
        partial[(size_t)blockIdx.x * 3 + 1] = ap;
        partial[(size_t)blockIdx.x * 3 + 2] = an;
    }
}

// Stage 2: deterministic reduce of per-block partials.
__global__ __launch_bounds__(256) void triplet_final_kernel(
    const double* __restrict__ partial, float* __restrict__ out, int nblocks, int T)
{
    __shared__ double red[256][3];
    double l = 0.0, ap = 0.0, an = 0.0;
    for (int i = threadIdx.x; i < nblocks; i += 256) {
        l  += partial[3 * (size_t)i + 0];
        ap += partial[3 * (size_t)i + 1];
        an += partial[3 * (size_t)i + 2];
    }
    red[threadIdx.x][0] = l;
    red[threadIdx.x][1] = ap;
    red[threadIdx.x][2] = an;
    __syncthreads();
    for (int s = 128; s > 0; s >>= 1) {
        if (threadIdx.x < s) {
            red[threadIdx.x][0] += red[threadIdx.x + s][0];
            red[threadIdx.x][1] += red[threadIdx.x + s][1];
            red[threadIdx.x][2] += red[threadIdx.x + s][2];
        }
        __syncthreads();
    }
    if (threadIdx.x == 0) {
        const double invT = 1.0 / (double)T;
        out[0] = (float)(red[0][0] * invT);
        out[1] = (float)(1.0 - red[0][1] * invT);
        out[2] = (float)(1.0 - red[0][2] * invT);
    }
}

extern "C" void kernel_launch(void* const* d_in, const int* in_sizes, int n_in,
                              void* d_out, int out_size, void* d_ws, size_t ws_size,
                              hipStream_t stream) {
    const float* emb = (const float*)d_in[0];
    const int* trip  = (const int*)d_in[1];
    const int D = 256;
    const int rows = in_sizes[0] / D;
    const int T = in_sizes[1] / 3;

    const size_t qBytes = (size_t)rows * D;              // 16 MiB int8 table
    const size_t sBytes = (size_t)rows * sizeof(float);  // 256 KiB scales
    const size_t pBytes = (size_t)NBLOCKS * 3 * sizeof(double);

    if (ws_size >= qBytes + sBytes + pBytes) {
        unsigned int* q = (unsigned int*)d_ws;
        float* scl      = (float*)((char*)d_ws + qBytes);
        double* partial = (double*)((char*)d_ws + qBytes + sBytes);

        convert_int8_kernel<<<CONV_BLOCKS, 256, 0, stream>>>(
            (const float4*)emb, q, scl, rows);
        triplet_partial_int8<<<NBLOCKS, BLOCK, 0, stream>>>(
            (const uint4*)q, scl, trip, partial, T);
        triplet_final_kernel<<<1, 256, 0, stream>>>(partial, (float*)d_out, NBLOCKS, T);
    } else {
        double* partial = (double*)d_ws;
        triplet_partial_kernel<<<NBLOCKS, BLOCK, 0, stream>>>(emb, trip, partial, T);
        triplet_final_kernel<<<1, 256, 0, stream>>>(partial, (float*)d_out, NBLOCKS, T);
    }
}

// Round 12
// 107.080 us; speedup vs baseline: 1.2787x; 1.0525x over previous
//
#include <hip/hip_runtime.h>

#define BLOCK 256
#define NBLOCKS 2048
#define WAVES_PER_BLOCK (BLOCK / 64)
#define GROUPS_PER_BLOCK (BLOCK / 16)
#define CONV_BLOCKS 4096

// ---- int4 dot primitive: hardware sdot8 if available, else software ----
#if defined(__has_builtin)
#  if __has_builtin(__builtin_amdgcn_sdot8)
#    define SDOT8(a, b, c) __builtin_amdgcn_sdot8((a), (b), (c), false)
#  endif
#endif
#ifndef SDOT8
__device__ __forceinline__ int sdot8_sw(int a, int b, int c) {
    #pragma unroll
    for (int k = 0; k < 8; ++k) {
        int ae = (a << (28 - 4 * k)) >> 28;
        int be = (b << (28 - 4 * k)) >> 28;
        c += ae * be;
    }
    return c;
}
#  define SDOT8(a, b, c) sdot8_sw((a), (b), (c))
#endif

// Pass 0: f32 table -> int4 table (per-row symmetric scale, [-7,7]) + f32 scales.
// One 64-lane wave per row: lane loads float4 (4 elems), wave-reduce max|x|,
// quantize to 4 nibbles packed in one ushort; 64 ushorts = 128B/row, coalesced.
__global__ __launch_bounds__(256) void convert_int4_kernel(
    const float4* __restrict__ emb4,        // [rows*64]
    unsigned short* __restrict__ q,         // [rows*64] 4 int4 per ushort
    float* __restrict__ scl,                // [rows]
    int rows)
{
    const int lane = threadIdx.x & 63;
    const int wid  = blockIdx.x * (blockDim.x >> 6) + (threadIdx.x >> 6);
    const int nw   = gridDim.x * (blockDim.x >> 6);
    for (int r = wid; r < rows; r += nw) {
        float4 v = emb4[(size_t)r * 64 + lane];
        float m = fmaxf(fmaxf(fabsf(v.x), fabsf(v.y)), fmaxf(fabsf(v.z), fabsf(v.w)));
        #pragma unroll
        for (int off = 1; off < 64; off <<= 1)
            m = fmaxf(m, __shfl_xor(m, off, 64));
        const float inv = 7.0f / m;
        int q0 = __float2int_rn(v.x * inv) & 15;
        int q1 = __float2int_rn(v.y * inv) & 15;
        int q2 = __float2int_rn(v.z * inv) & 15;
        int q3 = __float2int_rn(v.w * inv) & 15;
        q[(size_t)r * 64 + lane] =
            (unsigned short)(q0 | (q1 << 4) | (q2 << 8) | (q3 << 12));
        if (lane == 0) scl[r] = m * (1.0f / 7.0f);
    }
}

// Stage 1 (int4): 16-lane group per triplet; row = 128B = 16 x uint2.
// Lane lg holds bytes [lg*8, lg*8+8) of each row -> 2 sdot8 per pair,
// exact integer 16-lane butterfly reduce, then scale/clip/exp in f32.
__global__ __launch_bounds__(BLOCK) void triplet_partial_int4(
    const uint2* __restrict__ tabq,     // [rows*16]
    const float* __restrict__ scl,      // [rows]
    const int* __restrict__ trip,       // [T,3] int32
    double* __restrict__ partial,       // [gridDim.x,3]
    int T)
{
    const int lane = threadIdx.x & 63;
    const int lg   = lane & 15;
    const int g0   = blockIdx.x * GROUPS_PER_BLOCK + (threadIdx.x >> 4);
    const int ngroups = gridDim.x * GROUPS_PER_BLOCK;

    float s_loss = 0.f, s_apd = 0.f, s_and = 0.f;

    for (int t = g0; t < T; t += ngroups) {
        const int ia = trip[3 * t + 0];
        const int ip = trip[3 * t + 1];
        const int in_ = trip[3 * t + 2];

        const float sa = scl[ia];
        const float sp = scl[ip];
        const float sn = scl[in_];

        uint2 qa = tabq[(size_t)ia * 16 + lg];
        uint2 qp = tabq[(size_t)ip * 16 + lg];
        uint2 qn = tabq[(size_t)in_ * 16 + lg];

        int idap = 0, idan = 0;
        idap = SDOT8((int)qa.x, (int)qp.x, idap);
        idap = SDOT8((int)qa.y, (int)qp.y, idap);
        idan = SDOT8((int)qa.x, (int)qn.x, idan);
        idan = SDOT8((int)qa.y, (int)qn.y, idan);

        // exact integer reduce across the 16-lane group
        #pragma unroll
        for (int off = 1; off < 16; off <<= 1) {
            idap += __shfl_xor(idap, off, 64);
            idan += __shfl_xor(idan, off, 64);
        }

        float dap = (float)idap * (sa * sp);
        float dan = (float)idan * (sa * sn);

        dap = fminf(1.f, fmaxf(-1.f, dap));
        dan = fminf(1.f, fmaxf(-1.f, dan));

        s_loss += expf((dan - dap) * (1.0f / 0.7f));
        s_apd  += dap;
        s_and  += dan;
    }

    // 16 identical copies per group; butterfly then x1/16 (exact pow2)
    #pragma unroll
    for (int off = 1; off < 64; off <<= 1) {
        s_loss += __shfl_xor(s_loss, off, 64);
        s_apd  += __shfl_xor(s_apd,  off, 64);
        s_and  += __shfl_xor(s_and,  off, 64);
    }

    __shared__ double red[3][WAVES_PER_BLOCK];
    const int wid = threadIdx.x >> 6;
    if (lane == 0) {
        red[0][wid] = (double)s_loss * 0.0625;
        red[1][wid] = (double)s_apd  * 0.0625;
        red[2][wid] = (double)s_and  * 0.0625;
    }
    __syncthreads();
    if (threadIdx.x == 0) {
        double l = 0.0, ap = 0.0, an = 0.0;
        #pragma unroll
        for (int w = 0; w < WAVES_PER_BLOCK; ++w) {
            l += red[0][w]; ap += red[1][w]; an += red[2][w];
        }
        partial[(size_t)blockIdx.x * 3 + 0] = l;
        partial[(size_t)blockIdx.x * 3 + 1] = ap;
        partial[(size_t)blockIdx.x * 3 + 2] = an;
    }
}

// ---------- f32 fallback path (proven) ----------

__device__ __forceinline__ float dot4(float4 a, float4 b) {
    return a.x * b.x + a.y * b.y + a.z * b.z + a.w * b.w;
}

__global__ __launch_bounds__(BLOCK) void triplet_partial_kernel(
    const float* __restrict__ emb, const int* __restrict__ trip,
    double* __restrict__ partial, int T)
{
    const int lane = threadIdx.x & 63;
    const int lg   = lane & 15;
    const int g0   = blockIdx.x * GROUPS_PER_BLOCK + (threadIdx.x >> 4);
    const int ngroups = gridDim.x * GROUPS_PER_BLOCK;
    const float4* __restrict__ emb4 = (const float4*)emb;

    float s_loss = 0.f, s_apd = 0.f, s_and = 0.f;

    for (int t = g0; t < T; t += ngroups) {
        const int ia = trip[3 * t + 0];
        const int ip = trip[3 * t + 1];
        const int in_ = trip[3 * t + 2];
        const size_t ba = (size_t)ia * 64 + lg;
        const size_t bp = (size_t)ip * 64 + lg;
        const size_t bn = (size_t)in_ * 64 + lg;

        float4 a0 = emb4[ba], a1 = emb4[ba + 16], a2 = emb4[ba + 32], a3 = emb4[ba + 48];
        float4 p0 = emb4[bp], p1 = emb4[bp + 16], p2 = emb4[bp + 32], p3 = emb4[bp + 48];
        float4 n0 = emb4[bn], n1 = emb4[bn + 16], n2 = emb4[bn + 32], n3 = emb4[bn + 48];

        float dap = dot4(a0, p0) + dot4(a1, p1) + dot4(a2, p2) + dot4(a3, p3);
        float dan = dot4(a0, n0) + dot4(a1, n1) + dot4(a2, n2) + dot4(a3, n3);

        #pragma unroll
        for (int off = 1; off < 16; off <<= 1) {
            dap += __shfl_xor(dap, off, 64);
            dan += __shfl_xor(dan, off, 64);
        }

        dap = fminf(1.f, fmaxf(-1.f, dap));
        dan = fminf(1.f, fmaxf(-1.f, dan));

        s_loss += expf((dan - dap) * (1.0f / 0.7f));
        s_apd  += dap;
        s_and  += dan;
    }

    #pragma unroll
    for (int off = 1; off < 64; off <<= 1) {
        s_loss += __shfl_xor(s_loss, off, 64);
        s_apd  += __shfl_xor(s_apd,  off, 64);
        s_and  += __shfl_xor(s_and,  off, 64);
    }

    __shared__ double red[3][WAVES_PER_BLOCK];
    const int wid = threadIdx.x >> 6;
    if (lane == 0) {
        red[0][wid] = (double)s_loss * 0.0625;
        red[1][wid] = (double)s_apd  * 0.0625;
        red[2][wid] = (double)s_and  * 0.0625;
    }
    __syncthreads();
    if (threadIdx.x == 0) {
        double l = 0.0, ap = 0.0, an = 0.0;
        #pragma unroll
        for (int w = 0; w < WAVES_PER_BLOCK; ++w) {
            l += red[0][w]; ap += red[1][w]; an += red[2][w];
        }
        partial[(size_t)blockIdx.x * 3 + 0] = l;
        partial[(size_t)blockIdx.x * 3 + 1] = ap;
        partial[(size_t)blockIdx.x * 3 + 2] = an;
    }
}

// Stage 2: deterministic reduce of per-block partials.
__global__ __launch_bounds__(256) void triplet_final_kernel(
    const double* __restrict__ partial, float* __restrict__ out, int nblocks, int T)
{
    __shared__ double red[256][3];
    double l = 0.0, ap = 0.0, an = 0.0;
    for (int i = threadIdx.x; i < nblocks; i += 256) {
        l  += partial[3 * (size_t)i + 0];
        ap += partial[3 * (size_t)i + 1];
        an += partial[3 * (size_t)i + 2];
    }
    red[threadIdx.x][0] = l;
    red[threadIdx.x][1] = ap;
    red[threadIdx.x][2] = an;
    __syncthreads();
    for (int s = 128; s > 0; s >>= 1) {
        if (threadIdx.x < s) {
            red[threadIdx.x][0] += red[threadIdx.x + s][0];
            red[threadIdx.x][1] += red[threadIdx.x + s][1];
            red[threadIdx.x][2] += red[threadIdx.x + s][2];
        }
        __syncthreads();
    }
    if (threadIdx.x == 0) {
        const double invT = 1.0 / (double)T;
        out[0] = (float)(red[0][0] * invT);
        out[1] = (float)(1.0 - red[0][1] * invT);
        out[2] = (float)(1.0 - red[0][2] * invT);
    }
}

extern "C" void kernel_launch(void* const* d_in, const int* in_sizes, int n_in,
                              void* d_out, int out_size, void* d_ws, size_t ws_size,
                              hipStream_t stream) {
    const float* emb = (const float*)d_in[0];
    const int* trip  = (const int*)d_in[1];
    const int D = 256;
    const int rows = in_sizes[0] / D;
    const int T = in_sizes[1] / 3;

    const size_t qBytes = (size_t)rows * (D / 2);        // 8 MiB int4 table
    const size_t sBytes = (size_t)rows * sizeof(float);  // 256 KiB scales
    const size_t pBytes = (size_t)NBLOCKS * 3 * sizeof(double);

    if (ws_size >= qBytes + sBytes + pBytes) {
        unsigned short* q = (unsigned short*)d_ws;
        float* scl        = (float*)((char*)d_ws + qBytes);
        double* partial   = (double*)((char*)d_ws + qBytes + sBytes);

        convert_int4_kernel<<<CONV_BLOCKS, 256, 0, stream>>>(
            (const float4*)emb, q, scl, rows);
        triplet_partial_int4<<<NBLOCKS, BLOCK, 0, stream>>>(
            (const uint2*)q, scl, trip, partial, T);
        triplet_final_kernel<<<1, 256, 0, stream>>>(partial, (float*)d_out, NBLOCKS, T);
    } else {
        double* partial = (double*)d_ws;
        triplet_partial_kernel<<<NBLOCKS, BLOCK, 0, stream>>>(emb, trip, partial, T);
        triplet_final_kernel<<<1, 256, 0, stream>>>(partial, (float*)d_out, NBLOCKS, T);
    }
}